// Round 6
// baseline (47.665 us; speedup 1.0000x reference)
//
#include <hip/hip_runtime.h>
#include <stdint.h>

#define NROW  524288
#define BLK   256
#define NKNN  10
#define YCOLS 44
#define OCOLS 24     // dxdt(2) + dvdt(2) + dudt(20)

#define TBL    512
#define T2_LO  (-2.0f)
#define T3_LO  (0.0f)
#define T_H    (1.0f / 32.0f)     // span 16 over 512 entries
#define T_INVH 32.0f
// ws layout (floats): [0..1023] = T2 pairs (val,slope), [1024..2047] = T3 pairs, [2048] = o(100)
#define WS_T2   0
#define WS_T3   (2 * TBL)
#define WS_O100 (4 * TBL)

typedef float f32x4 __attribute__((ext_vector_type(4)));   // native vector for nontemporal builtins

// exact scalar -> 16 -> 8 -> 1 MLP from global weights
__device__ __forceinline__ float mlp_scalar_g(float s,
    const float* __restrict__ wa, const float* __restrict__ ba,
    const float* __restrict__ wb, const float* __restrict__ bb,
    const float* __restrict__ wc, const float* __restrict__ bc) {
    float h[16];
#pragma unroll
    for (int j = 0; j < 16; ++j)
        h[j] = fmaxf(fmaf(s, wa[j], ba[j]), 0.0f);
    float g[8];
#pragma unroll
    for (int k = 0; k < 8; ++k) g[k] = bb[k];
#pragma unroll
    for (int j = 0; j < 16; ++j) {
        float hj = h[j];
#pragma unroll
        for (int k = 0; k < 8; ++k)
            g[k] = fmaf(hj, wb[j * 8 + k], g[k]);
    }
    float o = bc[0];
#pragma unroll
    for (int k = 0; k < 8; ++k)
        o = fmaf(fmaxf(g[k], 0.0f), wc[k], o);
    return o;
}

// ---- setup kernel: tabulate (value, slope) pairs for the two scalar MLPs ----
__global__ __launch_bounds__(BLK) void table_kernel(
    const float* __restrict__ w2a, const float* __restrict__ b2a,
    const float* __restrict__ w2b, const float* __restrict__ b2b,
    const float* __restrict__ w2c, const float* __restrict__ b2c,
    const float* __restrict__ w3a, const float* __restrict__ b3a,
    const float* __restrict__ w3b, const float* __restrict__ b3b,
    const float* __restrict__ w3c, const float* __restrict__ b3c,
    float* __restrict__ ws)
{
    int g = blockIdx.x * BLK + threadIdx.x;
    if (g < TBL) {
        float s  = T2_LO + (float)g * T_H;
        float v0 = mlp_scalar_g(s,       w2a, b2a, w2b, b2b, w2c, b2c);
        float v1 = mlp_scalar_g(s + T_H, w2a, b2a, w2b, b2b, w2c, b2c);
        ws[WS_T2 + 2 * g + 0] = v0;
        ws[WS_T2 + 2 * g + 1] = v1 - v0;
    } else if (g < 2 * TBL) {
        int i = g - TBL;
        float s  = T3_LO + (float)i * T_H;
        float v0 = mlp_scalar_g(s,       w3a, b3a, w3b, b3b, w3c, b3c);
        float v1 = mlp_scalar_g(s + T_H, w3a, b3a, w3b, b3b, w3c, b3c);
        ws[WS_T3 + 2 * i + 0] = v0;
        ws[WS_T3 + 2 * i + 1] = v1 - v0;
    } else if (g == 2 * TBL) {
        ws[WS_O100] = mlp_scalar_g(100.0f, w2a, b2a, w2b, b2b, w2c, b2c);
    }
}

__device__ __forceinline__ float tbl_eval(const float2* __restrict__ T, float s, float lo) {
    float u = (s - lo) * T_INVH;
    u = fminf(fmaxf(u, 0.0f), (float)TBL - 1.001f);
    int i = (int)u;
    float f = u - (float)i;
    float2 e = T[i];               // one ds_read_b64
    return fmaf(f, e.y, e.x);
}

// ---- main kernel ----
__global__ __launch_bounds__(BLK, 6) void odefunc_kernel(
    const float* __restrict__ y,
    const float* __restrict__ w1a, const float* __restrict__ b1a,
    const float* __restrict__ w1b, const float* __restrict__ b1b,
    const float* __restrict__ ws,
    float* __restrict__ out)
{
    __shared__ float2 T2[TBL];     // 4 KB
    __shared__ float2 T3[TBL];     // 4 KB
    __shared__ f32x4 outs[BLK];    // 4 KB   -> 12 KB total

    const int t = threadIdx.x;
    const int row = blockIdx.x * BLK + t;

    // issue row loads FIRST so HBM latency hides under table staging
    const f32x4* yr = reinterpret_cast<const f32x4*>(y + (size_t)row * YCOLS);
    f32x4 a  = __builtin_nontemporal_load(yr + 0);   // x0, x1, vx, vy
    f32x4 u0 = __builtin_nontemporal_load(yr + 1);
    f32x4 u1 = __builtin_nontemporal_load(yr + 2);
    f32x4 u2 = __builtin_nontemporal_load(yr + 3);
    f32x4 u3 = __builtin_nontemporal_load(yr + 4);
    f32x4 u4 = __builtin_nontemporal_load(yr + 5);   // cols 4..23 = ux[10][2]

    // stage tables: 2048 floats = 512 float4, 2 per thread
    {
        const f32x4* g4 = reinterpret_cast<const f32x4*>(ws);
        f32x4* l2 = reinterpret_cast<f32x4*>(T2);  // 256 float4
        f32x4* l3 = reinterpret_cast<f32x4*>(T3);  // 256 float4
        l2[t] = g4[t];
        l3[t] = g4[t + 256];
    }
    const float o100 = ws[WS_O100];   // uniform scalar load
    __syncthreads();

    // ---- f1: door-direction MLP (4 -> 8 -> 2), weights via uniform s_loads ----
    float dx = 5.6f - a.x;
    float dy = 0.0f - a.y;
    float inv = rsqrtf(fmaf(dx, dx, dy * dy));
    float in1[4] = { dx * inv, dy * inv, a.z, a.w };
    float h1[8];
#pragma unroll
    for (int j = 0; j < 8; ++j) {
        float s = b1a[j];
#pragma unroll
        for (int k = 0; k < 4; ++k)
            s = fmaf(in1[k], w1a[k * 8 + j], s);
        h1[j] = fmaxf(s, 0.0f);
    }
    float f1x = b1b[0];
    float f1y = b1b[1];
#pragma unroll
    for (int j = 0; j < 8; ++j) {
        f1x = fmaf(h1[j], w1b[j * 2 + 0], f1x);
        f1y = fmaf(h1[j], w1b[j * 2 + 1], f1y);
    }

    // ---- f2: wall MLP via table ----
    bool corridor = (a.y < 1.0f) && (a.y > -1.0f);
    float o0 = tbl_eval(T2, a.x + 5.0f, T2_LO);
    float o1 = tbl_eval(T2, a.y + 5.0f, T2_LO);
    float o2 = tbl_eval(T2, 5.0f - a.y, T2_LO);
    float o3 = corridor ? o100 : tbl_eval(T2, 5.0f - a.x, T2_LO);
    float f2x = o0 - o3;
    float f2y = o1 - o2;

    // ---- f3: neighbor MLP via table ----
    float us[2 * NKNN] = { u0.x, u0.y, u0.z, u0.w,
                           u1.x, u1.y, u1.z, u1.w,
                           u2.x, u2.y, u2.z, u2.w,
                           u3.x, u3.y, u3.z, u3.w,
                           u4.x, u4.y, u4.z, u4.w };
    float f3x = 0.0f, f3y = 0.0f;
#pragma unroll
    for (int n = 0; n < NKNN; ++n) {
        float uxn = us[2 * n + 0];
        float uyn = us[2 * n + 1];
        float s2  = fmaf(uxn, uxn, uyn * uyn);
        float idn = rsqrtf(s2);
        float d   = s2 * idn;     // = sqrt(s2)
        float m   = tbl_eval(T3, d, T3_LO);
        float c   = m * idn;
        f3x = fmaf(-c, uxn, f3x);
        f3y = fmaf(-c, uyn, f3y);
    }

    // ---- combine + mask ----
    bool dead = (a.x > 5.0f);
    const float k80 = 1.0f / 80.0f;
    f32x4 r;
    r.x = dead ? 0.0f : a.z;
    r.y = dead ? 0.0f : a.w;
    r.z = dead ? 0.0f : (f1x + f2x + f3x) * k80;
    r.w = dead ? 0.0f : (f1y + f2y + f3y) * k80;
    outs[t] = r;
    __syncthreads();

    // coalesced store: out row = 24 floats = 6 float4; block region = 256*6 float4
    f32x4* o4 = reinterpret_cast<f32x4*>(out);
    const size_t base = (size_t)blockIdx.x * BLK * (OCOLS / 4);
    const f32x4 z = (f32x4)(0.0f);
#pragma unroll
    for (int i = 0; i < OCOLS / 4; ++i) {
        int idx = t + i * BLK;
        int rr = idx / (OCOLS / 4);
        int cc = idx - rr * (OCOLS / 4);
        f32x4 v = (cc == 0) ? outs[rr] : z;
        __builtin_nontemporal_store(v, &o4[base + idx]);
    }
}

extern "C" void kernel_launch(void* const* d_in, const int* in_sizes, int n_in,
                              void* d_out, int out_size, void* d_ws, size_t ws_size,
                              hipStream_t stream) {
    int iy = 1;
    for (int i = 0; i < n_in; ++i) {
        if (in_sizes[i] == NROW * YCOLS) { iy = i; break; }
    }
    const float* y   = (const float*)d_in[iy];
    const float* w1a = (const float*)d_in[iy + 1];
    const float* b1a = (const float*)d_in[iy + 2];
    const float* w1b = (const float*)d_in[iy + 3];
    const float* b1b = (const float*)d_in[iy + 4];
    const float* w2a = (const float*)d_in[iy + 5];
    const float* b2a = (const float*)d_in[iy + 6];
    const float* w2b = (const float*)d_in[iy + 7];
    const float* b2b = (const float*)d_in[iy + 8];
    const float* w2c = (const float*)d_in[iy + 9];
    const float* b2c = (const float*)d_in[iy + 10];
    const float* w3a = (const float*)d_in[iy + 11];
    const float* b3a = (const float*)d_in[iy + 12];
    const float* w3b = (const float*)d_in[iy + 13];
    const float* b3b = (const float*)d_in[iy + 14];
    const float* w3c = (const float*)d_in[iy + 15];
    const float* b3c = (const float*)d_in[iy + 16];
    float* out = (float*)d_out;
    float* ws  = (float*)d_ws;

    // 1) tabulate (val, slope) pairs (2*512 entries + o(100))
    hipLaunchKernelGGL(table_kernel, dim3((2 * TBL) / BLK + 1), dim3(BLK), 0, stream,
                       w2a, b2a, w2b, b2b, w2c, b2c,
                       w3a, b3a, w3b, b3b, w3c, b3c, ws);
    // 2) main pass
    hipLaunchKernelGGL(odefunc_kernel, dim3(NROW / BLK), dim3(BLK), 0, stream,
                       y, w1a, b1a, w1b, b1b, ws, out);
}

// Round 7
// 36.569 us; speedup vs baseline: 1.3034x; 1.3034x over previous
//
#include <hip/hip_runtime.h>
#include <stdint.h>

#define NROW  524288
#define BLK   256
#define RPT   2                  // rows per thread
#define NKNN  10
#define YCOLS 44
#define OCOLS 24     // dxdt(2) + dvdt(2) + dudt(20)

#define TBL    512
#define T2_LO  (-2.0f)
#define T3_LO  (0.0f)
#define T_H    (1.0f / 32.0f)     // span 16 over 512 entries
#define T_INVH 32.0f
// ws layout (floats): [0..1023] = T2 pairs (val,slope), [1024..2047] = T3 pairs, [2048] = o(100)
#define WS_T2   0
#define WS_T3   (2 * TBL)
#define WS_O100 (4 * TBL)

// exact scalar -> 16 -> 8 -> 1 MLP from global weights
__device__ __forceinline__ float mlp_scalar_g(float s,
    const float* __restrict__ wa, const float* __restrict__ ba,
    const float* __restrict__ wb, const float* __restrict__ bb,
    const float* __restrict__ wc, const float* __restrict__ bc) {
    float h[16];
#pragma unroll
    for (int j = 0; j < 16; ++j)
        h[j] = fmaxf(fmaf(s, wa[j], ba[j]), 0.0f);
    float g[8];
#pragma unroll
    for (int k = 0; k < 8; ++k) g[k] = bb[k];
#pragma unroll
    for (int j = 0; j < 16; ++j) {
        float hj = h[j];
#pragma unroll
        for (int k = 0; k < 8; ++k)
            g[k] = fmaf(hj, wb[j * 8 + k], g[k]);
    }
    float o = bc[0];
#pragma unroll
    for (int k = 0; k < 8; ++k)
        o = fmaf(fmaxf(g[k], 0.0f), wc[k], o);
    return o;
}

// ---- setup kernel: tabulate (value, slope) pairs for the two scalar MLPs ----
__global__ __launch_bounds__(BLK) void table_kernel(
    const float* __restrict__ w2a, const float* __restrict__ b2a,
    const float* __restrict__ w2b, const float* __restrict__ b2b,
    const float* __restrict__ w2c, const float* __restrict__ b2c,
    const float* __restrict__ w3a, const float* __restrict__ b3a,
    const float* __restrict__ w3b, const float* __restrict__ b3b,
    const float* __restrict__ w3c, const float* __restrict__ b3c,
    float* __restrict__ ws)
{
    int g = blockIdx.x * BLK + threadIdx.x;
    if (g < TBL) {
        float s  = T2_LO + (float)g * T_H;
        float v0 = mlp_scalar_g(s,       w2a, b2a, w2b, b2b, w2c, b2c);
        float v1 = mlp_scalar_g(s + T_H, w2a, b2a, w2b, b2b, w2c, b2c);
        ws[WS_T2 + 2 * g + 0] = v0;
        ws[WS_T2 + 2 * g + 1] = v1 - v0;
    } else if (g < 2 * TBL) {
        int i = g - TBL;
        float s  = T3_LO + (float)i * T_H;
        float v0 = mlp_scalar_g(s,       w3a, b3a, w3b, b3b, w3c, b3c);
        float v1 = mlp_scalar_g(s + T_H, w3a, b3a, w3b, b3b, w3c, b3c);
        ws[WS_T3 + 2 * i + 0] = v0;
        ws[WS_T3 + 2 * i + 1] = v1 - v0;
    } else if (g == 2 * TBL) {
        ws[WS_O100] = mlp_scalar_g(100.0f, w2a, b2a, w2b, b2b, w2c, b2c);
    }
}

__device__ __forceinline__ float tbl_eval(const float2* __restrict__ T, float s, float lo) {
    float u = (s - lo) * T_INVH;
    u = fminf(fmaxf(u, 0.0f), (float)TBL - 1.001f);
    int i = (int)u;
    float f = u - (float)i;
    float2 e = T[i];               // one ds_read_b64
    return fmaf(f, e.y, e.x);
}

// per-row physics given the 6 row float4s + tables
__device__ __forceinline__ float4 row_compute(
    float4 a, float4 u0, float4 u1, float4 u2, float4 u3, float4 u4,
    const float2* __restrict__ T2, const float2* __restrict__ T3, float o100,
    const float* __restrict__ w1a, const float* __restrict__ b1a,
    const float* __restrict__ w1b, const float* __restrict__ b1b)
{
    // ---- f1: door-direction MLP (4 -> 8 -> 2), weights via uniform s_loads ----
    float dx = 5.6f - a.x;
    float dy = 0.0f - a.y;
    float inv = rsqrtf(fmaf(dx, dx, dy * dy));
    float in1[4] = { dx * inv, dy * inv, a.z, a.w };
    float h1[8];
#pragma unroll
    for (int j = 0; j < 8; ++j) {
        float s = b1a[j];
#pragma unroll
        for (int k = 0; k < 4; ++k)
            s = fmaf(in1[k], w1a[k * 8 + j], s);
        h1[j] = fmaxf(s, 0.0f);
    }
    float f1x = b1b[0];
    float f1y = b1b[1];
#pragma unroll
    for (int j = 0; j < 8; ++j) {
        f1x = fmaf(h1[j], w1b[j * 2 + 0], f1x);
        f1y = fmaf(h1[j], w1b[j * 2 + 1], f1y);
    }

    // ---- f2: wall MLP via table ----
    bool corridor = (a.y < 1.0f) && (a.y > -1.0f);
    float o0 = tbl_eval(T2, a.x + 5.0f, T2_LO);
    float o1 = tbl_eval(T2, a.y + 5.0f, T2_LO);
    float o2 = tbl_eval(T2, 5.0f - a.y, T2_LO);
    float o3 = corridor ? o100 : tbl_eval(T2, 5.0f - a.x, T2_LO);
    float f2x = o0 - o3;
    float f2y = o1 - o2;

    // ---- f3: neighbor MLP via table ----
    float us[2 * NKNN] = { u0.x, u0.y, u0.z, u0.w,
                           u1.x, u1.y, u1.z, u1.w,
                           u2.x, u2.y, u2.z, u2.w,
                           u3.x, u3.y, u3.z, u3.w,
                           u4.x, u4.y, u4.z, u4.w };
    float f3x = 0.0f, f3y = 0.0f;
#pragma unroll
    for (int n = 0; n < NKNN; ++n) {
        float uxn = us[2 * n + 0];
        float uyn = us[2 * n + 1];
        float s2  = fmaf(uxn, uxn, uyn * uyn);
        float idn = rsqrtf(s2);
        float d   = s2 * idn;     // = sqrt(s2)
        float m   = tbl_eval(T3, d, T3_LO);
        float c   = m * idn;
        f3x = fmaf(-c, uxn, f3x);
        f3y = fmaf(-c, uyn, f3y);
    }

    bool dead = (a.x > 5.0f);
    const float k80 = 1.0f / 80.0f;
    float4 r;
    r.x = dead ? 0.0f : a.z;
    r.y = dead ? 0.0f : a.w;
    r.z = dead ? 0.0f : (f1x + f2x + f3x) * k80;
    r.w = dead ? 0.0f : (f1y + f2y + f3y) * k80;
    return r;
}

// ---- main kernel: 2 rows per thread ----
__global__ __launch_bounds__(BLK) void odefunc_kernel(
    const float* __restrict__ y,
    const float* __restrict__ w1a, const float* __restrict__ b1a,
    const float* __restrict__ w1b, const float* __restrict__ b1b,
    const float* __restrict__ ws,
    float* __restrict__ out)
{
    __shared__ float2 T2[TBL];           // 4 KB
    __shared__ float2 T3[TBL];           // 4 KB
    __shared__ float4 outs[BLK * RPT];   // 8 KB  -> 16 KB total

    const int t = threadIdx.x;
    const int r0 = blockIdx.x * (BLK * RPT) + t;       // rows r0 and r0+BLK

    // issue ALL row loads first (12 independent dwordx4) so HBM latency
    // overlaps table staging + compute
    const float4* ya = reinterpret_cast<const float4*>(y + (size_t)r0 * YCOLS);
    const float4* yb = reinterpret_cast<const float4*>(y + (size_t)(r0 + BLK) * YCOLS);
    float4 a0 = ya[0], p0 = ya[1], p1 = ya[2], p2 = ya[3], p3 = ya[4], p4 = ya[5];
    float4 a1 = yb[0], q0 = yb[1], q1 = yb[2], q2 = yb[3], q3 = yb[4], q4 = yb[5];

    // stage tables: 2048 floats = 512 float4, 2 per thread
    {
        const float4* g4 = reinterpret_cast<const float4*>(ws);
        float4* l2 = reinterpret_cast<float4*>(T2);
        float4* l3 = reinterpret_cast<float4*>(T3);
        l2[t] = g4[t];
        l3[t] = g4[t + 256];
    }
    const float o100 = ws[WS_O100];   // uniform scalar load
    __syncthreads();

    outs[t]       = row_compute(a0, p0, p1, p2, p3, p4, T2, T3, o100, w1a, b1a, w1b, b1b);
    outs[t + BLK] = row_compute(a1, q0, q1, q2, q3, q4, T2, T3, o100, w1a, b1a, w1b, b1b);
    __syncthreads();

    // coalesced store: 512 rows * 6 float4 = 3072 float4, 12 per thread
    float4* o4 = reinterpret_cast<float4*>(out);
    const size_t base = (size_t)blockIdx.x * (BLK * RPT) * (OCOLS / 4);
    const float4 z = make_float4(0.0f, 0.0f, 0.0f, 0.0f);
#pragma unroll
    for (int i = 0; i < RPT * OCOLS / 4; ++i) {
        int idx = t + i * BLK;           // 0 .. 3071
        int rr = idx / (OCOLS / 4);
        int cc = idx - rr * (OCOLS / 4);
        o4[base + idx] = (cc == 0) ? outs[rr] : z;
    }
}

extern "C" void kernel_launch(void* const* d_in, const int* in_sizes, int n_in,
                              void* d_out, int out_size, void* d_ws, size_t ws_size,
                              hipStream_t stream) {
    int iy = 1;
    for (int i = 0; i < n_in; ++i) {
        if (in_sizes[i] == NROW * YCOLS) { iy = i; break; }
    }
    const float* y   = (const float*)d_in[iy];
    const float* w1a = (const float*)d_in[iy + 1];
    const float* b1a = (const float*)d_in[iy + 2];
    const float* w1b = (const float*)d_in[iy + 3];
    const float* b1b = (const float*)d_in[iy + 4];
    const float* w2a = (const float*)d_in[iy + 5];
    const float* b2a = (const float*)d_in[iy + 6];
    const float* w2b = (const float*)d_in[iy + 7];
    const float* b2b = (const float*)d_in[iy + 8];
    const float* w2c = (const float*)d_in[iy + 9];
    const float* b2c = (const float*)d_in[iy + 10];
    const float* w3a = (const float*)d_in[iy + 11];
    const float* b3a = (const float*)d_in[iy + 12];
    const float* w3b = (const float*)d_in[iy + 13];
    const float* b3b = (const float*)d_in[iy + 14];
    const float* w3c = (const float*)d_in[iy + 15];
    const float* b3c = (const float*)d_in[iy + 16];
    float* out = (float*)d_out;
    float* ws  = (float*)d_ws;

    // 1) tabulate (val, slope) pairs (2*512 entries + o(100))
    hipLaunchKernelGGL(table_kernel, dim3((2 * TBL) / BLK + 1), dim3(BLK), 0, stream,
                       w2a, b2a, w2b, b2b, w2c, b2c,
                       w3a, b3a, w3b, b3b, w3c, b3c, ws);
    // 2) main pass: 2 rows/thread
    hipLaunchKernelGGL(odefunc_kernel, dim3(NROW / (BLK * RPT)), dim3(BLK), 0, stream,
                       y, w1a, b1a, w1b, b1b, ws, out);
}

// Round 8
// 34.779 us; speedup vs baseline: 1.3705x; 1.0515x over previous
//
#include <hip/hip_runtime.h>
#include <stdint.h>

#define NROW  524288
#define BLK   256
#define NKNN  10
#define YCOLS 44
#define OCOLS 24     // dxdt(2) + dvdt(2) + dudt(20)

#define TBL    512
#define T2_LO  (-2.0f)
#define T3_LO  (0.0f)
#define T_H    (1.0f / 32.0f)     // span 16 over 512 entries
#define T_INVH 32.0f
// ws layout (floats): [0..1023] = T2 pairs (val,slope), [1024..2047] = T3 pairs, [2048] = o(100)
#define WS_T2   0
#define WS_T3   (2 * TBL)
#define WS_O100 (4 * TBL)

// exact scalar -> 16 -> 8 -> 1 MLP from global weights
__device__ __forceinline__ float mlp_scalar_g(float s,
    const float* __restrict__ wa, const float* __restrict__ ba,
    const float* __restrict__ wb, const float* __restrict__ bb,
    const float* __restrict__ wc, const float* __restrict__ bc) {
    float h[16];
#pragma unroll
    for (int j = 0; j < 16; ++j)
        h[j] = fmaxf(fmaf(s, wa[j], ba[j]), 0.0f);
    float g[8];
#pragma unroll
    for (int k = 0; k < 8; ++k) g[k] = bb[k];
#pragma unroll
    for (int j = 0; j < 16; ++j) {
        float hj = h[j];
#pragma unroll
        for (int k = 0; k < 8; ++k)
            g[k] = fmaf(hj, wb[j * 8 + k], g[k]);
    }
    float o = bc[0];
#pragma unroll
    for (int k = 0; k < 8; ++k)
        o = fmaf(fmaxf(g[k], 0.0f), wc[k], o);
    return o;
}

// ---- setup kernel: tabulate (value, slope) pairs for the two scalar MLPs ----
__global__ __launch_bounds__(BLK) void table_kernel(
    const float* __restrict__ w2a, const float* __restrict__ b2a,
    const float* __restrict__ w2b, const float* __restrict__ b2b,
    const float* __restrict__ w2c, const float* __restrict__ b2c,
    const float* __restrict__ w3a, const float* __restrict__ b3a,
    const float* __restrict__ w3b, const float* __restrict__ b3b,
    const float* __restrict__ w3c, const float* __restrict__ b3c,
    float* __restrict__ ws)
{
    int g = blockIdx.x * BLK + threadIdx.x;
    if (g < TBL) {
        float s  = T2_LO + (float)g * T_H;
        float v0 = mlp_scalar_g(s,       w2a, b2a, w2b, b2b, w2c, b2c);
        float v1 = mlp_scalar_g(s + T_H, w2a, b2a, w2b, b2b, w2c, b2c);
        ws[WS_T2 + 2 * g + 0] = v0;
        ws[WS_T2 + 2 * g + 1] = v1 - v0;
    } else if (g < 2 * TBL) {
        int i = g - TBL;
        float s  = T3_LO + (float)i * T_H;
        float v0 = mlp_scalar_g(s,       w3a, b3a, w3b, b3b, w3c, b3c);
        float v1 = mlp_scalar_g(s + T_H, w3a, b3a, w3b, b3b, w3c, b3c);
        ws[WS_T3 + 2 * i + 0] = v0;
        ws[WS_T3 + 2 * i + 1] = v1 - v0;
    } else if (g == 2 * TBL) {
        ws[WS_O100] = mlp_scalar_g(100.0f, w2a, b2a, w2b, b2b, w2c, b2c);
    }
}

__device__ __forceinline__ float tbl_eval(const float2* __restrict__ T, float s, float lo) {
    float u = (s - lo) * T_INVH;
    u = fminf(fmaxf(u, 0.0f), (float)TBL - 1.001f);
    int i = (int)u;
    float f = u - (float)i;
    float2 e = T[i];               // one ds_read_b64
    return fmaf(f, e.y, e.x);
}

// ---- main kernel: 1 row per thread ----
__global__ __launch_bounds__(BLK) void odefunc_kernel(
    const float* __restrict__ y,
    const float* __restrict__ w1a, const float* __restrict__ b1a,
    const float* __restrict__ w1b, const float* __restrict__ b1b,
    const float* __restrict__ ws,
    float* __restrict__ out)
{
    __shared__ float2 T2[TBL];     // 4 KB
    __shared__ float2 T3[TBL];     // 4 KB
    __shared__ float4 outs[BLK];   // 4 KB   -> 12 KB total

    const int t = threadIdx.x;
    const int row = blockIdx.x * BLK + t;

    // issue all 6 row loads FIRST so memory latency hides under table staging
    const float4* yr = reinterpret_cast<const float4*>(y + (size_t)row * YCOLS);
    float4 a  = yr[0];            // x0, x1, vx, vy
    float4 u0 = yr[1];
    float4 u1 = yr[2];
    float4 u2 = yr[3];
    float4 u3 = yr[4];
    float4 u4 = yr[5];            // cols 4..23 = ux[10][2]

    // stage tables: 2048 floats = 512 float4, 2 per thread
    {
        const float4* g4 = reinterpret_cast<const float4*>(ws);
        float4* l2 = reinterpret_cast<float4*>(T2);
        float4* l3 = reinterpret_cast<float4*>(T3);
        l2[t] = g4[t];
        l3[t] = g4[t + 256];
    }
    const float o100 = ws[WS_O100];   // uniform scalar load
    __syncthreads();

    // ---- f1: door-direction MLP (4 -> 8 -> 2), weights via uniform s_loads ----
    float dx = 5.6f - a.x;
    float dy = 0.0f - a.y;
    float inv = rsqrtf(fmaf(dx, dx, dy * dy));
    float in1[4] = { dx * inv, dy * inv, a.z, a.w };
    float h1[8];
#pragma unroll
    for (int j = 0; j < 8; ++j) {
        float s = b1a[j];
#pragma unroll
        for (int k = 0; k < 4; ++k)
            s = fmaf(in1[k], w1a[k * 8 + j], s);
        h1[j] = fmaxf(s, 0.0f);
    }
    float f1x = b1b[0];
    float f1y = b1b[1];
#pragma unroll
    for (int j = 0; j < 8; ++j) {
        f1x = fmaf(h1[j], w1b[j * 2 + 0], f1x);
        f1y = fmaf(h1[j], w1b[j * 2 + 1], f1y);
    }

    // ---- f2: wall MLP via table ----
    bool corridor = (a.y < 1.0f) && (a.y > -1.0f);
    float o0 = tbl_eval(T2, a.x + 5.0f, T2_LO);
    float o1 = tbl_eval(T2, a.y + 5.0f, T2_LO);
    float o2 = tbl_eval(T2, 5.0f - a.y, T2_LO);
    float o3 = corridor ? o100 : tbl_eval(T2, 5.0f - a.x, T2_LO);
    float f2x = o0 - o3;
    float f2y = o1 - o2;

    // ---- f3: neighbor MLP via table ----
    float us[2 * NKNN] = { u0.x, u0.y, u0.z, u0.w,
                           u1.x, u1.y, u1.z, u1.w,
                           u2.x, u2.y, u2.z, u2.w,
                           u3.x, u3.y, u3.z, u3.w,
                           u4.x, u4.y, u4.z, u4.w };
    float f3x = 0.0f, f3y = 0.0f;
#pragma unroll
    for (int n = 0; n < NKNN; ++n) {
        float uxn = us[2 * n + 0];
        float uyn = us[2 * n + 1];
        float s2  = fmaf(uxn, uxn, uyn * uyn);
        float idn = rsqrtf(s2);
        float d   = s2 * idn;     // = sqrt(s2)
        float m   = tbl_eval(T3, d, T3_LO);
        float c   = m * idn;
        f3x = fmaf(-c, uxn, f3x);
        f3y = fmaf(-c, uyn, f3y);
    }

    // ---- combine + mask ----
    bool dead = (a.x > 5.0f);
    const float k80 = 1.0f / 80.0f;
    float4 r;
    r.x = dead ? 0.0f : a.z;
    r.y = dead ? 0.0f : a.w;
    r.z = dead ? 0.0f : (f1x + f2x + f3x) * k80;
    r.w = dead ? 0.0f : (f1y + f2y + f3y) * k80;
    outs[t] = r;
    __syncthreads();

    // coalesced store: out row = 24 floats = 6 float4; block region = 256*6 float4
    float4* o4 = reinterpret_cast<float4*>(out);
    const size_t base = (size_t)blockIdx.x * BLK * (OCOLS / 4);
    const float4 z = make_float4(0.0f, 0.0f, 0.0f, 0.0f);
#pragma unroll
    for (int i = 0; i < OCOLS / 4; ++i) {
        int idx = t + i * BLK;
        int rr = idx / (OCOLS / 4);
        int cc = idx - rr * (OCOLS / 4);
        o4[base + idx] = (cc == 0) ? outs[rr] : z;
    }
}

extern "C" void kernel_launch(void* const* d_in, const int* in_sizes, int n_in,
                              void* d_out, int out_size, void* d_ws, size_t ws_size,
                              hipStream_t stream) {
    int iy = 1;
    for (int i = 0; i < n_in; ++i) {
        if (in_sizes[i] == NROW * YCOLS) { iy = i; break; }
    }
    const float* y   = (const float*)d_in[iy];
    const float* w1a = (const float*)d_in[iy + 1];
    const float* b1a = (const float*)d_in[iy + 2];
    const float* w1b = (const float*)d_in[iy + 3];
    const float* b1b = (const float*)d_in[iy + 4];
    const float* w2a = (const float*)d_in[iy + 5];
    const float* b2a = (const float*)d_in[iy + 6];
    const float* w2b = (const float*)d_in[iy + 7];
    const float* b2b = (const float*)d_in[iy + 8];
    const float* w2c = (const float*)d_in[iy + 9];
    const float* b2c = (const float*)d_in[iy + 10];
    const float* w3a = (const float*)d_in[iy + 11];
    const float* b3a = (const float*)d_in[iy + 12];
    const float* w3b = (const float*)d_in[iy + 13];
    const float* b3b = (const float*)d_in[iy + 14];
    const float* w3c = (const float*)d_in[iy + 15];
    const float* b3c = (const float*)d_in[iy + 16];
    float* out = (float*)d_out;
    float* ws  = (float*)d_ws;

    // 1) tabulate (val, slope) pairs (2*512 entries + o(100))
    hipLaunchKernelGGL(table_kernel, dim3((2 * TBL) / BLK + 1), dim3(BLK), 0, stream,
                       w2a, b2a, w2b, b2b, w2c, b2c,
                       w3a, b3a, w3b, b3b, w3c, b3c, ws);
    // 2) main pass: 1 row/thread
    hipLaunchKernelGGL(odefunc_kernel, dim3(NROW / BLK), dim3(BLK), 0, stream,
                       y, w1a, b1a, w1b, b1b, ws, out);
}

// Round 9
// 31.294 us; speedup vs baseline: 1.5232x; 1.1114x over previous
//
#include <hip/hip_runtime.h>
#include <stdint.h>

#define NROW  524288
#define BLK   256
#define NKNN  10
#define YCOLS 44
#define OCOLS 24     // dxdt(2) + dvdt(2) + dudt(20)

#define TBL    512
#define T2_LO  (-2.0f)
#define T3_LO  (0.0f)
#define T_H    (1.0f / 32.0f)     // span 16 over 512 entries
#define T_INVH 32.0f
// ws layout (floats): [0..1023] = T2 pairs (val,slope), [1024..2047] = T3 pairs, [2048] = o(100)
#define WS_T2   0
#define WS_T3   (2 * TBL)
#define WS_O100 (4 * TBL)

// exact scalar -> 16 -> 8 -> 1 MLP from global weights
__device__ __forceinline__ float mlp_scalar_g(float s,
    const float* __restrict__ wa, const float* __restrict__ ba,
    const float* __restrict__ wb, const float* __restrict__ bb,
    const float* __restrict__ wc, const float* __restrict__ bc) {
    float h[16];
#pragma unroll
    for (int j = 0; j < 16; ++j)
        h[j] = fmaxf(fmaf(s, wa[j], ba[j]), 0.0f);
    float g[8];
#pragma unroll
    for (int k = 0; k < 8; ++k) g[k] = bb[k];
#pragma unroll
    for (int j = 0; j < 16; ++j) {
        float hj = h[j];
#pragma unroll
        for (int k = 0; k < 8; ++k)
            g[k] = fmaf(hj, wb[j * 8 + k], g[k]);
    }
    float o = bc[0];
#pragma unroll
    for (int k = 0; k < 8; ++k)
        o = fmaf(fmaxf(g[k], 0.0f), wc[k], o);
    return o;
}

// ---- setup kernel: tabulate (value, slope) pairs for the two scalar MLPs ----
__global__ __launch_bounds__(BLK) void table_kernel(
    const float* __restrict__ w2a, const float* __restrict__ b2a,
    const float* __restrict__ w2b, const float* __restrict__ b2b,
    const float* __restrict__ w2c, const float* __restrict__ b2c,
    const float* __restrict__ w3a, const float* __restrict__ b3a,
    const float* __restrict__ w3b, const float* __restrict__ b3b,
    const float* __restrict__ w3c, const float* __restrict__ b3c,
    float* __restrict__ ws)
{
    int g = blockIdx.x * BLK + threadIdx.x;
    if (g < TBL) {
        float s  = T2_LO + (float)g * T_H;
        float v0 = mlp_scalar_g(s,       w2a, b2a, w2b, b2b, w2c, b2c);
        float v1 = mlp_scalar_g(s + T_H, w2a, b2a, w2b, b2b, w2c, b2c);
        ws[WS_T2 + 2 * g + 0] = v0;
        ws[WS_T2 + 2 * g + 1] = v1 - v0;
    } else if (g < 2 * TBL) {
        int i = g - TBL;
        float s  = T3_LO + (float)i * T_H;
        float v0 = mlp_scalar_g(s,       w3a, b3a, w3b, b3b, w3c, b3c);
        float v1 = mlp_scalar_g(s + T_H, w3a, b3a, w3b, b3b, w3c, b3c);
        ws[WS_T3 + 2 * i + 0] = v0;
        ws[WS_T3 + 2 * i + 1] = v1 - v0;
    } else if (g == 2 * TBL) {
        ws[WS_O100] = mlp_scalar_g(100.0f, w2a, b2a, w2b, b2b, w2c, b2c);
    }
}

__device__ __forceinline__ float tbl_eval(const float2* __restrict__ T, float s, float lo) {
    float u = (s - lo) * T_INVH;
    u = fminf(fmaxf(u, 0.0f), (float)TBL - 1.001f);
    int i = (int)u;
    float f = u - (float)i;
    float2 e = T[i];               // one ds_read_b64
    return fmaf(f, e.y, e.x);
}

// ---- main kernel: streaming loads remapped through LDS ----
__global__ __launch_bounds__(BLK) void odefunc_kernel(
    const float* __restrict__ y,
    const float* __restrict__ w1a, const float* __restrict__ b1a,
    const float* __restrict__ w1b, const float* __restrict__ b1b,
    const float* __restrict__ ws,
    float* __restrict__ out)
{
    __shared__ float4 S[BLK * 6];  // 24 KB: staging for y-in, reused for out
    __shared__ float2 T2[TBL];     // 4 KB
    __shared__ float2 T3[TBL];     // 4 KB   -> 32 KB total

    const int t = threadIdx.x;

    // ---- phase 1: near-contiguous load of the block's useful 1536 float4 ----
    // block's y region = 256 rows * 11 float4; useful = cc 0..5 of each row.
    const float4* yb = reinterpret_cast<const float4*>(y) + (size_t)blockIdx.x * BLK * (YCOLS / 4);
    float4 ld[6];
#pragma unroll
    for (int i = 0; i < 6; ++i) {
        int j  = t + i * BLK;          // 0 .. 1535 (compact index)
        int rr = j / 6;
        int cc = j - rr * 6;
        ld[i] = yb[rr * 11 + cc];      // lanes span ~15 lines/instr (vs 88 scattered)
    }
    // table staging (2 float4/thread)
    {
        const float4* g4 = reinterpret_cast<const float4*>(ws);
        reinterpret_cast<float4*>(T2)[t] = g4[t];
        reinterpret_cast<float4*>(T3)[t] = g4[t + 256];
    }
#pragma unroll
    for (int i = 0; i < 6; ++i)
        S[t + i * BLK] = ld[i];        // linear LDS write, conflict-free
    const float o100 = ws[WS_O100];    // uniform scalar load
    __syncthreads();

    // ---- phase 2: thread t computes row t from LDS ----
    float4 a  = S[t * 6 + 0];          // x0, x1, vx, vy
    float4 u0 = S[t * 6 + 1];
    float4 u1 = S[t * 6 + 2];
    float4 u2 = S[t * 6 + 3];
    float4 u3 = S[t * 6 + 4];
    float4 u4 = S[t * 6 + 5];

    // f1: door-direction MLP (4 -> 8 -> 2), weights via uniform s_loads
    float dx = 5.6f - a.x;
    float dy = 0.0f - a.y;
    float inv = rsqrtf(fmaf(dx, dx, dy * dy));
    float in1[4] = { dx * inv, dy * inv, a.z, a.w };
    float h1[8];
#pragma unroll
    for (int j = 0; j < 8; ++j) {
        float s = b1a[j];
#pragma unroll
        for (int k = 0; k < 4; ++k)
            s = fmaf(in1[k], w1a[k * 8 + j], s);
        h1[j] = fmaxf(s, 0.0f);
    }
    float f1x = b1b[0];
    float f1y = b1b[1];
#pragma unroll
    for (int j = 0; j < 8; ++j) {
        f1x = fmaf(h1[j], w1b[j * 2 + 0], f1x);
        f1y = fmaf(h1[j], w1b[j * 2 + 1], f1y);
    }

    // f2: wall MLP via table
    bool corridor = (a.y < 1.0f) && (a.y > -1.0f);
    float o0 = tbl_eval(T2, a.x + 5.0f, T2_LO);
    float o1 = tbl_eval(T2, a.y + 5.0f, T2_LO);
    float o2 = tbl_eval(T2, 5.0f - a.y, T2_LO);
    float o3 = corridor ? o100 : tbl_eval(T2, 5.0f - a.x, T2_LO);
    float f2x = o0 - o3;
    float f2y = o1 - o2;

    // f3: neighbor MLP via table
    float us[2 * NKNN] = { u0.x, u0.y, u0.z, u0.w,
                           u1.x, u1.y, u1.z, u1.w,
                           u2.x, u2.y, u2.z, u2.w,
                           u3.x, u3.y, u3.z, u3.w,
                           u4.x, u4.y, u4.z, u4.w };
    float f3x = 0.0f, f3y = 0.0f;
#pragma unroll
    for (int n = 0; n < NKNN; ++n) {
        float uxn = us[2 * n + 0];
        float uyn = us[2 * n + 1];
        float s2  = fmaf(uxn, uxn, uyn * uyn);
        float idn = rsqrtf(s2);
        float d   = s2 * idn;     // = sqrt(s2)
        float m   = tbl_eval(T3, d, T3_LO);
        float c   = m * idn;
        f3x = fmaf(-c, uxn, f3x);
        f3y = fmaf(-c, uyn, f3y);
    }

    // combine + mask
    bool dead = (a.x > 5.0f);
    const float k80 = 1.0f / 80.0f;
    float4 r;
    r.x = dead ? 0.0f : a.z;
    r.y = dead ? 0.0f : a.w;
    r.z = dead ? 0.0f : (f1x + f2x + f3x) * k80;
    r.w = dead ? 0.0f : (f1y + f2y + f3y) * k80;

    // overwrite OWN row of S with the output row {r, 0,0,0,0,0}
    // (no barrier needed: slot t*6.. is only touched by thread t)
    const float4 z = make_float4(0.0f, 0.0f, 0.0f, 0.0f);
    S[t * 6 + 0] = r;
    S[t * 6 + 1] = z;
    S[t * 6 + 2] = z;
    S[t * 6 + 3] = z;
    S[t * 6 + 4] = z;
    S[t * 6 + 5] = z;
    __syncthreads();

    // ---- phase 3: pure linear stream LDS -> global (matches out row = 6 float4) ----
    float4* o4 = reinterpret_cast<float4*>(out) + (size_t)blockIdx.x * BLK * (OCOLS / 4);
#pragma unroll
    for (int i = 0; i < 6; ++i)
        o4[t + i * BLK] = S[t + i * BLK];
}

extern "C" void kernel_launch(void* const* d_in, const int* in_sizes, int n_in,
                              void* d_out, int out_size, void* d_ws, size_t ws_size,
                              hipStream_t stream) {
    int iy = 1;
    for (int i = 0; i < n_in; ++i) {
        if (in_sizes[i] == NROW * YCOLS) { iy = i; break; }
    }
    const float* y   = (const float*)d_in[iy];
    const float* w1a = (const float*)d_in[iy + 1];
    const float* b1a = (const float*)d_in[iy + 2];
    const float* w1b = (const float*)d_in[iy + 3];
    const float* b1b = (const float*)d_in[iy + 4];
    const float* w2a = (const float*)d_in[iy + 5];
    const float* b2a = (const float*)d_in[iy + 6];
    const float* w2b = (const float*)d_in[iy + 7];
    const float* b2b = (const float*)d_in[iy + 8];
    const float* w2c = (const float*)d_in[iy + 9];
    const float* b2c = (const float*)d_in[iy + 10];
    const float* w3a = (const float*)d_in[iy + 11];
    const float* b3a = (const float*)d_in[iy + 12];
    const float* w3b = (const float*)d_in[iy + 13];
    const float* b3b = (const float*)d_in[iy + 14];
    const float* w3c = (const float*)d_in[iy + 15];
    const float* b3c = (const float*)d_in[iy + 16];
    float* out = (float*)d_out;
    float* ws  = (float*)d_ws;

    // 1) tabulate (val, slope) pairs (2*512 entries + o(100))
    hipLaunchKernelGGL(table_kernel, dim3((2 * TBL) / BLK + 1), dim3(BLK), 0, stream,
                       w2a, b2a, w2b, b2b, w2c, b2c,
                       w3a, b3a, w3b, b3b, w3c, b3c, ws);
    // 2) main pass
    hipLaunchKernelGGL(odefunc_kernel, dim3(NROW / BLK), dim3(BLK), 0, stream,
                       y, w1a, b1a, w1b, b1b, ws, out);
}